// Round 4
// baseline (28517.102 us; speedup 1.0000x reference)
//
#include <hip/hip_runtime.h>
#include <stdint.h>
#include <stddef.h>

typedef unsigned short ushort_t;
typedef __attribute__((ext_vector_type(8))) short short8;
typedef __attribute__((ext_vector_type(4))) float floatx4;

#define T_STEPS 1024
#define BATCH   128
#define HID     512
#define NBLK    128
#define NTHR    512
#define INV_KEEP 1.4285714285714286f

// Per-block generation flags, one per 128B line: g_sync[b*32], b in [0,128).
// flag = k  <=>  block finished all writes AND reads of intervals < k-? :
//   concretely: after init, flag=1; after completing interval u, flag=u+2.
__device__ unsigned g_sync[4096];

struct Params {
  const float* xs;
  const float* Wih1; const float* Whh1; const float* bih1; const float* bhh1;
  const float* Wih2; const float* Whh2; const float* bih2; const float* bhh2;
  const float* mask;
  float* out;
  char* ws;
};

// Lag-1 all-flag wait: proceed when every block has completed interval
// (target-1). Wave 0 polls 2 flags/lane (128 flags), then acquire-fence.
__device__ __forceinline__ void waitgen(unsigned target) {
  if (threadIdx.x < 64) {
    const int l = threadIdx.x;
    for (;;) {
      unsigned a = __hip_atomic_load(&g_sync[l * 32], __ATOMIC_RELAXED,
                                     __HIP_MEMORY_SCOPE_AGENT);
      unsigned b = __hip_atomic_load(&g_sync[(l + 64) * 32], __ATOMIC_RELAXED,
                                     __HIP_MEMORY_SCOPE_AGENT);
      if (__all(a >= target && b >= target)) break;
      __builtin_amdgcn_s_sleep(1);
    }
    __threadfence();   // acquire: subsequent reads see peers' h/x writes
  }
  __syncthreads();
}

// Publish completion: all stores drained (syncthreads), release-fence, flag.
__device__ __forceinline__ void postgen(unsigned value) {
  __syncthreads();
  if (threadIdx.x == 0) {
    __threadfence();
    __hip_atomic_store(&g_sync[blockIdx.x * 32], value, __ATOMIC_RELAXED,
                       __HIP_MEMORY_SCOPE_AGENT);
  }
}

__device__ __forceinline__ ushort_t f2b(float a) {  // RTNE f32->bf16
  unsigned u = __float_as_uint(a);
  u += 0x7FFFu + ((u >> 16) & 1u);
  return (ushort_t)(u >> 16);
}

// ws layout (bytes):
//   [0,       524288)  (unused)
//   [524288, 1048576)  h1: par{0,1} x {hi,lo} bf16 [128][512]  (par*262144 + which*131072)
//   [1048576,1572864)  h2: same
//   [1572864,2097152)  x slab: par{0,1} x {hi,lo} bf16 [128][512]
//
// Block decomposition (128 blocks x 512 thr): layer = bid>>6; c8 = bid&63 owns
// 8 h-cols [c8*8, c8*8+8) for ALL 128 batch rows. 8 waves/block = 16 rows each.
// 1 block/CU (128KB LDS) -> 8 waves/CU = 2 waves/SIMD (2x round-3 occupancy).
//
// NOTE: init zeroing covers ONLY the h slabs [524288, 1572864). The x slab is
// written (x(t=0)) by other blocks concurrently before the first flag —
// zeroing it here is a cross-block race (round-2 bug, absmax 1.17).
__global__ __launch_bounds__(NTHR, 1) void lstm_persist(Params p) {
  extern __shared__ ushort_t Wl[];  // 128 KB: hi at [0,32768), lo at [32768,65536)

  char* ws = p.ws;
  auto H1HI = [&](int par) { return (ushort_t*)(ws + 524288 + par * 262144); };
  auto H1LO = [&](int par) { return (ushort_t*)(ws + 524288 + par * 262144 + 131072); };
  auto H2HI = [&](int par) { return (ushort_t*)(ws + 1048576 + par * 262144); };
  auto H2LO = [&](int par) { return (ushort_t*)(ws + 1048576 + par * 262144 + 131072); };
  auto XSHI = [&](int par) { return (ushort_t*)(ws + 1572864 + par * 262144); };
  auto XSLO = [&](int par) { return (ushort_t*)(ws + 1572864 + par * 262144 + 131072); };

  const int bid = blockIdx.x, tid = threadIdx.x;
  const int gtid = bid * NTHR + tid;            // 0..65535
  const int layer = bid >> 6;
  const int c8 = bid & 63;                      // col-group: 8 h-cols
  const int lane = tid & 63, w = tid >> 6;      // 8 waves, 16 batch rows each
  const int jj = lane & 15, quad = lane >> 4;
  const int rbase = w * 16;

  const float* Wih = layer ? p.Wih2 : p.Wih1;
  const float* Whh = layer ? p.Whh2 : p.Whh1;
  const float* bih = layer ? p.bih2 : p.bih1;
  const float* bhh = layer ? p.bhh2 : p.bhh1;

  // ---- one-time: weights -> LDS as bf16 hi/lo (32 gate-cols x 1024 k) ----
  for (int i = tid; i < 32768; i += NTHR) {
    int e = i & 7, jjw = (i >> 3) & 15, ntw = (i >> 7) & 1, kg = i >> 8;
    int k = kg * 8 + e;
    int col = ((jjw >> 2) << 9) + c8 * 8 + ntw * 4 + (jjw & 3);  // gate*512 + hcol
    float wv = (k < 512) ? Wih[col * 512 + k] : Whh[col * 512 + (k - 512)];
    unsigned uw = __float_as_uint(wv);
    Wl[i] = (ushort_t)(uw >> 16);                       // trunc hi
    float wf = __uint_as_float(uw & 0xFFFF0000u);
    Wl[32768 + i] = f2b(wv - wf);                       // RTNE lo
  }
  // ---- zero h slabs ONLY (both parities): bytes [524288, 1572864) ----
  {
    uint4 zz = {0u, 0u, 0u, 0u};
    uint4* dst = (uint4*)(ws + 524288);
    for (int i = gtid; i < 65536; i += NBLK * NTHR) dst[i] = zz;
  }
  // ---- convert x(t=0) into slab par 0 ----
  {
    float v = p.xs[gtid];
    unsigned uv = __float_as_uint(v);
    XSHI(0)[gtid] = (ushort_t)(uv >> 16);
    float hf = __uint_as_float(uv & 0xFFFF0000u);
    XSLO(0)[gtid] = f2b(v - hf);
  }
  // ---- per-lane constants: bias sums and dropout factors; c in registers ----
  float bsum[2];
#pragma unroll
  for (int nt = 0; nt < 2; ++nt) {
    int colW = ((jj >> 2) << 9) + c8 * 8 + nt * 4 + (jj & 3);
    bsum[nt] = bih[colW] + bhh[colW];
  }
  float dpre[2][4];
  float creg[2][4];
#pragma unroll
  for (int nt = 0; nt < 2; ++nt)
#pragma unroll
    for (int e = 0; e < 4; ++e) {
      int r = rbase + quad * 4 + e;
      int hgc = c8 * 8 + nt * 4 + (lane & 3);
      dpre[nt][e] = p.mask[r * 512 + hgc] * INV_KEEP;
      creg[nt][e] = 0.f;
    }

  postgen(1);  // init writes (zeroing, x(0)) published

  const int rowbyte = ((rbase + jj) * 512 + quad * 8) * 2;  // A-frag byte offset
  const bool dostore = (jj < 4);  // 4 shuffle-subgroups compute identical h; store once

#pragma unroll 1
  for (unsigned u = 0; u <= T_STEPS; ++u) {
    // ---- issue x(u+1) HBM load early: latency hides under the flag wait ----
    const bool havex = (u + 2 <= T_STEPS);
    float xv = 0.f;
    if (havex) xv = p.xs[(size_t)(u + 1) * 65536 + gtid];

    waitgen(u + 1);  // all peers completed interval u-1 (lag-1 barrier)

    // ---- write x(u+1) into slab (u+1)&1 (WAR-safe only after waitgen) ----
    if (havex) {
      unsigned uv = __float_as_uint(xv);
      int pn = (u + 1) & 1;
      XSHI(pn)[gtid] = (ushort_t)(uv >> 16);
      float hf = __uint_as_float(uv & 0xFFFF0000u);
      XSLO(pn)[gtid] = f2b(xv - hf);
    }

    const bool active = layer ? (u >= 1) : (u < T_STEPS);
    if (active) {
      const int t = layer ? (int)u - 1 : (int)u;
      const int pu = (int)u & 1, pv = pu ^ 1;
      // A sources: low half (k<512) and high half (k>=512), hi/lo each
      const ushort_t *aLoHi, *aLoLo, *aHiHi, *aHiLo;
      ushort_t *whHi, *whLo;
      if (layer == 0) {
        aLoHi = XSHI(pu); aLoLo = XSLO(pu);    // x(u)
        aHiHi = H1HI(pv); aHiLo = H1LO(pv);    // h1(u-1)
        whHi = H1HI(pu);  whLo = H1LO(pu);     // write h1(u)
      } else {
        aLoHi = H1HI(pv); aLoLo = H1LO(pv);    // h1(u-1) = h1(t)
        aHiHi = H2HI(pu); aHiLo = H2LO(pu);    // h2(u-2) = h2(t-1)
        whHi = H2HI(pv);  whLo = H2LO(pv);     // write h2(t)
      }

      floatx4 acc[2];
      acc[0] = (floatx4){bsum[0], bsum[0], bsum[0], bsum[0]};
      acc[1] = (floatx4){bsum[1], bsum[1], bsum[1], bsum[1]};

      auto ldchunk = [&](int c, uint4* dst) {
        const char* bh = (const char*)((c < 8) ? aLoHi : aHiHi);
        const char* bl = (const char*)((c < 8) ? aLoLo : aHiLo);
        int kb = (c & 7) * 128;
#pragma unroll
        for (int ks = 0; ks < 2; ++ks) {
          int off = rowbyte + kb + ks * 64;
          dst[ks * 2 + 0] = *(const uint4*)(bh + off);
          dst[ks * 2 + 1] = *(const uint4*)(bl + off);
        }
      };

      uint4 ring[4][4];
      ldchunk(0, ring[0]);
      ldchunk(1, ring[1]);
      ldchunk(2, ring[2]);
#pragma unroll
      for (int c = 0; c < 16; ++c) {
        if (c < 13) ldchunk(c + 3, ring[(c + 3) & 3]);
        uint4* cur = ring[c & 3];
#pragma unroll
        for (int ks = 0; ks < 2; ++ks) {
          short8 ahf = *(const short8*)&cur[ks * 2 + 0];
          short8 alf = *(const short8*)&cur[ks * 2 + 1];
#pragma unroll
          for (int nt = 0; nt < 2; ++nt) {
            int o = (((c * 8 + ks * 4 + quad) * 2 + nt) * 16 + jj) * 8;
            short8 bhf = *(const short8*)&Wl[o];
            short8 blf = *(const short8*)&Wl[32768 + o];
            acc[nt] = __builtin_amdgcn_mfma_f32_16x16x32_bf16(ahf, bhf, acc[nt], 0, 0, 0);
            acc[nt] = __builtin_amdgcn_mfma_f32_16x16x32_bf16(ahf, blf, acc[nt], 0, 0, 0);
            acc[nt] = __builtin_amdgcn_mfma_f32_16x16x32_bf16(alf, bhf, acc[nt], 0, 0, 0);
          }
        }
      }

      // ---- epilogue: shuffle-gather gates, cell update (c in regs), store ----
      const int sb = (lane & 48) | (lane & 3);
#pragma unroll
      for (int nt = 0; nt < 2; ++nt)
#pragma unroll
        for (int e = 0; e < 4; ++e) {
          float v = acc[nt][e];
          float gi = __shfl(v, sb + 0, 64);
          float gf = __shfl(v, sb + 4, 64);
          float gg = __shfl(v, sb + 8, 64);
          float go = __shfl(v, sb + 12, 64);
          float si = 1.f / (1.f + __expf(-gi));
          float sf = 1.f / (1.f + __expf(-gf));
          float so = 1.f / (1.f + __expf(-go));
          float tg = 2.f / (1.f + __expf(-2.f * gg)) - 1.f;
          int r = rbase + quad * 4 + e;
          int hgc = c8 * 8 + nt * 4 + (lane & 3);
          int ci = r * 512 + hgc;
          float cn = sf * creg[nt][e] + si * tg;
          float tc = 2.f / (1.f + __expf(-2.f * cn)) - 1.f;
          float hn = so * tc;
          float d = dpre[nt][e];
          hn *= d; cn *= d;
          creg[nt][e] = cn;
          if (dostore) {
            unsigned uh = __float_as_uint(hn);
            whHi[ci] = (ushort_t)(uh >> 16);
            float hf = __uint_as_float(uh & 0xFFFF0000u);
            whLo[ci] = f2b(hn - hf);
            if (layer) p.out[(size_t)t * 65536 + ci] = hn;
          }
        }
    }
    if (u < T_STEPS) postgen(u + 2);  // publish interval u; last interval: exit is sync
  }
}

extern "C" void kernel_launch(void* const* d_in, const int* in_sizes, int n_in,
                              void* d_out, int out_size, void* d_ws, size_t ws_size,
                              hipStream_t stream) {
  (void)in_sizes; (void)n_in; (void)out_size; (void)ws_size;
  Params p;
  p.xs   = (const float*)d_in[0];
  p.Wih1 = (const float*)d_in[1];
  p.Whh1 = (const float*)d_in[2];
  p.bih1 = (const float*)d_in[3];
  p.bhh1 = (const float*)d_in[4];
  p.Wih2 = (const float*)d_in[5];
  p.Whh2 = (const float*)d_in[6];
  p.bih2 = (const float*)d_in[7];
  p.bhh2 = (const float*)d_in[8];
  p.mask = (const float*)d_in[9];
  p.out  = (float*)d_out;
  p.ws   = (char*)d_ws;   // needs 2 MiB

  static bool attr_done = false;
  if (!attr_done) {
    (void)hipFuncSetAttribute(reinterpret_cast<const void*>(lstm_persist),
                              hipFuncAttributeMaxDynamicSharedMemorySize, 131072);
    attr_done = true;
  }

  void* sym = nullptr;
  hipGetSymbolAddress(&sym, HIP_SYMBOL(g_sync));
  hipMemsetAsync(sym, 0, 4096 * sizeof(unsigned), stream);

  void* args[] = { &p };
  hipLaunchCooperativeKernel(reinterpret_cast<void*>(lstm_persist),
                             dim3(NBLK), dim3(NTHR), args, 131072, stream);
}

// Round 5
// 24296.516 us; speedup vs baseline: 1.1737x; 1.1737x over previous
//
#include <hip/hip_runtime.h>
#include <stdint.h>
#include <stddef.h>

typedef unsigned short ushort_t;
typedef __attribute__((ext_vector_type(8))) short short8;
typedef __attribute__((ext_vector_type(4))) float floatx4;
typedef __attribute__((ext_vector_type(4))) unsigned uintx4;

#define T_STEPS 1024
#define BATCH   128
#define HID     512
#define NBLK    256
#define NTHR    512
#define INV_KEEP 1.4285714285714286f

// Per-block generation flags, one per 128B line: g_sync[b*32], b in [0,256).
__device__ unsigned g_sync[8192];

struct Params {
  const float* xs;
  const float* Wih1; const float* Whh1; const float* bih1; const float* bhh1;
  const float* Wih2; const float* Whh2; const float* bih2; const float* bhh2;
  const float* mask;
  float* out;
  char* ws;
};

// Lag-1 all-flag wait: proceed when every block has completed interval
// (target-1). Wave 0 polls 4 flags/lane (256 flags), then acquire-fence.
__device__ __forceinline__ void waitgen(unsigned target) {
  if (threadIdx.x < 64) {
    const int l = threadIdx.x;
    for (;;) {
      unsigned a = __hip_atomic_load(&g_sync[l * 32], __ATOMIC_RELAXED,
                                     __HIP_MEMORY_SCOPE_AGENT);
      unsigned b = __hip_atomic_load(&g_sync[(l + 64) * 32], __ATOMIC_RELAXED,
                                     __HIP_MEMORY_SCOPE_AGENT);
      unsigned c = __hip_atomic_load(&g_sync[(l + 128) * 32], __ATOMIC_RELAXED,
                                     __HIP_MEMORY_SCOPE_AGENT);
      unsigned d = __hip_atomic_load(&g_sync[(l + 192) * 32], __ATOMIC_RELAXED,
                                     __HIP_MEMORY_SCOPE_AGENT);
      if (__all(a >= target && b >= target && c >= target && d >= target)) break;
      __builtin_amdgcn_s_sleep(1);
    }
    __threadfence();   // acquire: subsequent reads see peers' h/x writes
  }
  __syncthreads();
}

__device__ __forceinline__ void postgen(unsigned value) {
  __syncthreads();
  if (threadIdx.x == 0) {
    __threadfence();
    __hip_atomic_store(&g_sync[blockIdx.x * 32], value, __ATOMIC_RELAXED,
                       __HIP_MEMORY_SCOPE_AGENT);
  }
}

__device__ __forceinline__ ushort_t f2b(float a) {  // RTNE f32->bf16
  unsigned u = __float_as_uint(a);
  u += 0x7FFFu + ((u >> 16) & 1u);
  return (ushort_t)(u >> 16);
}

// ws layout (bytes):
//   [524288, 1048576)  h1: par{0,1} x {hi,lo} bf16 [128][512]
//   [1048576,1572864)  h2: same
//   [1572864,2097152)  x slab: par{0,1} x {hi,lo} bf16 [128][512]
//
// Blocks (256): layer = bid>>7; c8 = (bid&127)>>1 (8 h-cols); bhalf = bid&1
// (64 batch rows). 8 waves: kh = w>>2 picks k-half (0: x|h1-part, 1: h-part),
// rg = w&3 picks 16 rows. Partial gates reduced via LDS scratch.
// Per wave: 32 16B loads/step, ALL issued up front via asm global_load_dwordx4,
// consumed with counted vmcnt (Little's law: ~1 MB in flight grid-wide).
__global__ __launch_bounds__(NTHR, 2) void lstm_persist(Params p) {
  extern __shared__ ushort_t Wl[];  // 128KB weights (hi/lo) + 9216B reduce scratch

  char* ws = p.ws;
  auto H1HI = [&](int par) { return (ushort_t*)(ws + 524288 + par * 262144); };
  auto H1LO = [&](int par) { return (ushort_t*)(ws + 524288 + par * 262144 + 131072); };
  auto H2HI = [&](int par) { return (ushort_t*)(ws + 1048576 + par * 262144); };
  auto H2LO = [&](int par) { return (ushort_t*)(ws + 1048576 + par * 262144 + 131072); };
  auto XSHI = [&](int par) { return (ushort_t*)(ws + 1572864 + par * 262144); };
  auto XSLO = [&](int par) { return (ushort_t*)(ws + 1572864 + par * 262144 + 131072); };

  const int bid = blockIdx.x, tid = threadIdx.x;
  const int gtid = bid * NTHR + tid;            // 0..131071
  const int layer = bid >> 7;
  const int c8 = (bid & 127) >> 1;              // col-group: 8 h-cols
  const int bhalf = bid & 1;                    // batch half: 64 rows
  const int lane = tid & 63, w = tid >> 6;
  const int kh = w >> 2, rg = w & 3;            // k-half, row-group
  const int jj = lane & 15, quad = lane >> 4;
  const int rbase = bhalf * 64 + rg * 16;

  const float* Wih = layer ? p.Wih2 : p.Wih1;
  const float* Whh = layer ? p.Whh2 : p.Whh1;
  const float* bih = layer ? p.bih2 : p.bih1;
  const float* bhh = layer ? p.bhh2 : p.bhh1;

  // ---- one-time: weights -> LDS as bf16 hi/lo (32 gate-cols x 1024 k) ----
  for (int i = tid; i < 32768; i += NTHR) {
    int e = i & 7, jjw = (i >> 3) & 15, ntw = (i >> 7) & 1, kg = i >> 8;
    int k = kg * 8 + e;
    int col = ((jjw >> 2) << 9) + c8 * 8 + ntw * 4 + (jjw & 3);  // gate*512 + hcol
    float wv = (k < 512) ? Wih[col * 512 + k] : Whh[col * 512 + (k - 512)];
    unsigned uw = __float_as_uint(wv);
    Wl[i] = (ushort_t)(uw >> 16);                       // trunc hi
    float wf = __uint_as_float(uw & 0xFFFF0000u);
    Wl[32768 + i] = f2b(wv - wf);                       // RTNE lo
  }
  // ---- zero h slabs ONLY (both parities): bytes [524288, 1572864) ----
  {
    uint4 zz = {0u, 0u, 0u, 0u};
    uint4* dst = (uint4*)(ws + 524288);
    for (int i = gtid; i < 65536; i += NBLK * NTHR) dst[i] = zz;
  }
  // ---- convert x(t=0) into slab par 0 (one writer per element) ----
  if (gtid < 65536) {
    float v = p.xs[gtid];
    unsigned uv = __float_as_uint(v);
    XSHI(0)[gtid] = (ushort_t)(uv >> 16);
    float hf = __uint_as_float(uv & 0xFFFF0000u);
    XSLO(0)[gtid] = f2b(v - hf);
  }
  // ---- per-lane constants ----
  float bsum[2];
#pragma unroll
  for (int nt = 0; nt < 2; ++nt) {
    int colW = ((jj >> 2) << 9) + c8 * 8 + nt * 4 + (jj & 3);
    bsum[nt] = bih[colW] + bhh[colW];
  }
  float dpre[2][4];
  float creg[2][4];
#pragma unroll
  for (int nt = 0; nt < 2; ++nt)
#pragma unroll
    for (int e = 0; e < 4; ++e) {
      int r = rbase + quad * 4 + e;
      int hgc = c8 * 8 + nt * 4 + (lane & 3);
      dpre[nt][e] = p.mask[r * 512 + hgc] * INV_KEEP;
      creg[nt][e] = 0.f;
    }

  postgen(1);  // init writes (zeroing, x(0)) published

  const int rowbyte = ((rbase + jj) * 512 + quad * 8) * 2;  // A-frag byte offset
  float* red = (float*)((char*)Wl + 131072);                // reduce scratch

#pragma unroll 1
  for (unsigned u = 0; u <= T_STEPS; ++u) {
    // ---- issue x(u+1) HBM load early: latency hides under the flag wait ----
    const bool havex = (u + 2 <= T_STEPS) && (gtid < 65536);
    float xv = 0.f;
    if (havex) xv = p.xs[(size_t)(u + 1) * 65536 + gtid];

    waitgen(u + 1);  // all peers completed interval u-1

    if (havex) {
      unsigned uv = __float_as_uint(xv);
      int pn = (u + 1) & 1;
      XSHI(pn)[gtid] = (ushort_t)(uv >> 16);
      float hf = __uint_as_float(uv & 0xFFFF0000u);
      XSLO(pn)[gtid] = f2b(xv - hf);
    }

    const bool active = layer ? (u >= 1) : (u < T_STEPS);
    if (active) {
      const int t = layer ? (int)u - 1 : (int)u;
      const int pu = (int)u & 1, pv = pu ^ 1;
      const ushort_t *aLoHi, *aLoLo, *aHiHi, *aHiLo;
      ushort_t *whHi, *whLo;
      if (layer == 0) {
        aLoHi = XSHI(pu); aLoLo = XSLO(pu);    // x(u)
        aHiHi = H1HI(pv); aHiLo = H1LO(pv);    // h1(u-1)
        whHi = H1HI(pu);  whLo = H1LO(pu);     // write h1(u)
      } else {
        aLoHi = H1HI(pv); aLoLo = H1LO(pv);    // h1(u-1) = h1(t)
        aHiHi = H2HI(pu); aHiLo = H2LO(pu);    // h2(u-2) = h2(t-1)
        whHi = H2HI(pv);  whLo = H2LO(pv);     // write h2(t)
      }
      // this wave's k-half source slab
      const char* bh = (const char*)(kh ? aHiHi : aLoHi);
      const char* bl = (const char*)(kh ? aHiLo : aLoLo);

      floatx4 acc[2];
      if (kh) { acc[0] = (floatx4){0.f, 0.f, 0.f, 0.f}; acc[1] = acc[0]; }
      else {
        acc[0] = (floatx4){bsum[0], bsum[0], bsum[0], bsum[0]};
        acc[1] = (floatx4){bsum[1], bsum[1], bsum[1], bsum[1]};
      }

      // drain stray VMEM (x load/store, prior-step stores) for exact vmcnt counting
      asm volatile("s_waitcnt vmcnt(0)" ::: "memory");

      uintx4 rq[8][4];
      // ---- issue ALL 32 loads up front (asm: compiler won't hold this depth) ----
#define ISSUE(C)                                                               \
  {                                                                            \
    const char* a0 = bh + rowbyte + (C)*128;                                   \
    const char* a1 = bl + rowbyte + (C)*128;                                   \
    asm volatile("global_load_dwordx4 %0, %1, off"                             \
                 : "=v"(rq[C][0]) : "v"(a0));                                  \
    asm volatile("global_load_dwordx4 %0, %1, off"                             \
                 : "=v"(rq[C][1]) : "v"(a1));                                  \
    asm volatile("global_load_dwordx4 %0, %1, off offset:64"                   \
                 : "=v"(rq[C][2]) : "v"(a0));                                  \
    asm volatile("global_load_dwordx4 %0, %1, off offset:64"                   \
                 : "=v"(rq[C][3]) : "v"(a1));                                  \
  }
      ISSUE(0) ISSUE(1) ISSUE(2) ISSUE(3) ISSUE(4) ISSUE(5) ISSUE(6) ISSUE(7)
#undef ISSUE

      auto dochunk = [&](const uintx4& h0, const uintx4& l0,
                         const uintx4& h1, const uintx4& l1, int gc) {
#pragma unroll
        for (int ks = 0; ks < 2; ++ks) {
          const uintx4& ch = ks ? h1 : h0;
          const uintx4& cl = ks ? l1 : l0;
          short8 ahf = *(const short8*)&ch;
          short8 alf = *(const short8*)&cl;
#pragma unroll
          for (int nt = 0; nt < 2; ++nt) {
            int o = (((gc * 8 + ks * 4 + quad) * 2 + nt) * 16 + jj) * 8;
            short8 bhf = *(const short8*)&Wl[o];
            short8 blf = *(const short8*)&Wl[32768 + o];
            acc[nt] = __builtin_amdgcn_mfma_f32_16x16x32_bf16(ahf, bhf, acc[nt], 0, 0, 0);
            acc[nt] = __builtin_amdgcn_mfma_f32_16x16x32_bf16(ahf, blf, acc[nt], 0, 0, 0);
            acc[nt] = __builtin_amdgcn_mfma_f32_16x16x32_bf16(alf, bhf, acc[nt], 0, 0, 0);
          }
        }
      };

      // ---- consume with counted vmcnt (oldest 4(c+1) retired <=> vmcnt 28-4c) ----
#define CONS(C, NW)                                                            \
  asm volatile("s_waitcnt vmcnt(" #NW ")");                                    \
  __builtin_amdgcn_sched_barrier(0);                                           \
  dochunk(rq[C][0], rq[C][1], rq[C][2], rq[C][3], kh * 8 + (C));
      CONS(0, 28) CONS(1, 24) CONS(2, 20) CONS(3, 16)
      CONS(4, 12) CONS(5, 8)  CONS(6, 4)  CONS(7, 0)
#undef CONS

      // ---- cross-k reduction: kh=1 partials -> LDS -> kh=0 adds ----
      if (kh) {
        int base = (tid - 256) * 9;
#pragma unroll
        for (int nt = 0; nt < 2; ++nt)
#pragma unroll
          for (int e = 0; e < 4; ++e) red[base + nt * 4 + e] = acc[nt][e];
      }
      __syncthreads();
      if (!kh) {
        int base = tid * 9;
#pragma unroll
        for (int nt = 0; nt < 2; ++nt)
#pragma unroll
          for (int e = 0; e < 4; ++e) acc[nt][e] += red[base + nt * 4 + e];

        // ---- epilogue: shuffle-gather gates, cell update, store ----
        const int sb = (lane & 48) | (lane & 3);
        const bool dostore = (jj < 4);
#pragma unroll
        for (int nt = 0; nt < 2; ++nt)
#pragma unroll
          for (int e = 0; e < 4; ++e) {
            float v = acc[nt][e];
            float gi = __shfl(v, sb + 0, 64);
            float gf = __shfl(v, sb + 4, 64);
            float gg = __shfl(v, sb + 8, 64);
            float go = __shfl(v, sb + 12, 64);
            float si = 1.f / (1.f + __expf(-gi));
            float sf = 1.f / (1.f + __expf(-gf));
            float so = 1.f / (1.f + __expf(-go));
            float tg = 2.f / (1.f + __expf(-2.f * gg)) - 1.f;
            int r = rbase + quad * 4 + e;
            int hgc = c8 * 8 + nt * 4 + (lane & 3);
            int ci = r * 512 + hgc;
            float cn = sf * creg[nt][e] + si * tg;
            float tc = 2.f / (1.f + __expf(-2.f * cn)) - 1.f;
            float hn = so * tc;
            float d = dpre[nt][e];
            hn *= d; cn *= d;
            creg[nt][e] = cn;
            if (dostore) {
              unsigned uh = __float_as_uint(hn);
              whHi[ci] = (ushort_t)(uh >> 16);
              float hf = __uint_as_float(uh & 0xFFFF0000u);
              whLo[ci] = f2b(hn - hf);
              if (layer) p.out[(size_t)t * 65536 + ci] = hn;
            }
          }
      }
    }
    if (u < T_STEPS) postgen(u + 2);  // last interval: kernel exit is the sync
  }
}

extern "C" void kernel_launch(void* const* d_in, const int* in_sizes, int n_in,
                              void* d_out, int out_size, void* d_ws, size_t ws_size,
                              hipStream_t stream) {
  (void)in_sizes; (void)n_in; (void)out_size; (void)ws_size;
  Params p;
  p.xs   = (const float*)d_in[0];
  p.Wih1 = (const float*)d_in[1];
  p.Whh1 = (const float*)d_in[2];
  p.bih1 = (const float*)d_in[3];
  p.bhh1 = (const float*)d_in[4];
  p.Wih2 = (const float*)d_in[5];
  p.Whh2 = (const float*)d_in[6];
  p.bih2 = (const float*)d_in[7];
  p.bhh2 = (const float*)d_in[8];
  p.mask = (const float*)d_in[9];
  p.out  = (float*)d_out;
  p.ws   = (char*)d_ws;   // needs 2 MiB

  static bool attr_done = false;
  if (!attr_done) {
    (void)hipFuncSetAttribute(reinterpret_cast<const void*>(lstm_persist),
                              hipFuncAttributeMaxDynamicSharedMemorySize, 140288);
    attr_done = true;
  }

  void* sym = nullptr;
  hipGetSymbolAddress(&sym, HIP_SYMBOL(g_sync));
  hipMemsetAsync(sym, 0, 8192 * sizeof(unsigned), stream);

  void* args[] = { &p };
  hipLaunchCooperativeKernel(reinterpret_cast<void*>(lstm_persist),
                             dim3(NBLK), dim3(NTHR), args, 140288, stream);
}